// Round 12
// baseline (237.142 us; speedup 1.0000x reference)
//
#include <hip/hip_runtime.h>

// Causal depthwise conv1d: y[b,s,h] = sum_j x[b,s-3+j,h] * w[h,j], * mask[b,s]
// B=4, S=4096, H=2048, K=4, fp32.
//
// Ledger: R3/R8/R11/R12 (concurrent R/W, <=32KB/CU reads in flight) = 79-83us;
// R13 (temporal R/W epochs, 128KB bursts at ~50% duty) ~= 75-77us (healthy-
// container bench arithmetic, R11 round). Revised Little's law with LOADED
// latency ~2.5-3us: ~60-100KB/CU of reads must be in flight CONTINUOUSLY for
// ~6 TB/s. Never tested. R14 = R12's DMA ring at depth 4: counted vmcnt holds
// 3 tiles (96KB/CU over 2 blocks) in flight with no idle window; stores free-
// run; no vmcnt(0) anywhere in-loop.
// Ring invariant: iter i reads tile i from ring[i&3]; DMA(i+3) (issued iter i,
// after iter i-1's trailing barrier) overwrites ring[(i-1)&3] -- so halo rows
// carry in registers (h3<-h1, h2<-L0, h1<-L1), never read back from LDS.
// Exact vmcnt (2 DMA + 2 ST per wave per iter): newer-than-DMA(i) ops =
//   i=0: DMA(1,2,3)=6 | i=1: DMA(2,3),ST(0),DMA(4)=8 | i=2: 10 | 3<=i<=NT-4: 12
//   tail mirrors: NT-3:10, NT-2:8, NT-1:6 (no new DMA issued).
// Predict: kernel 50-62us (bench 208-220) if depth is the lever; gates LDS=64KB,
// VGPR 56-72, WRITE ~131MB. Pre-commit: gates OK but kernel >=72us => ROOFLINE.

constexpr int B_    = 4;
constexpr int S_    = 4096;
constexpr int H_    = 2048;
constexpr int H4    = H_ / 4;              // 512 float4 per row
constexpr int TPB   = 512;                 // thread t == column h4
constexpr int TROWS = 2;                   // rows per tile
constexpr int TILE4 = TROWS * H4;          // 1024 float4 = 16 KiB
constexpr int SPANR = 32;                  // rows per block (never crosses batch)
constexpr int NT    = SPANR / TROWS;       // 16 tiles per block
constexpr int NBLK  = B_ * S_ / SPANR;     // 512 blocks = 2 per CU

typedef float f32x4 __attribute__((ext_vector_type(4)));

// Stage one 2-row (16 KiB) tile via direct-to-LDS DMA: 2 ops x 1KB per wave.
// LDS dest is wave-uniform base + lane*16 (m104) == linear layout of gsrc.
__device__ __forceinline__ void stage2(const float4* gsrc, float4* lbuf,
                                       int wv, int ln) {
    #pragma unroll
    for (int j = 0; j < 2; ++j) {
        const int fo = (wv * 2 + j) * 64;            // float4 offset of 1KB chunk
        __builtin_amdgcn_global_load_lds(
            (const __attribute__((address_space(1))) void*)(gsrc + fo + ln),
            (__attribute__((address_space(3))) void*)(lbuf + fo),
            16, 0, 0);
    }
}

__device__ __forceinline__ f32x4 conv_row(const float4& x3, const float4& x2,
                                          const float4& x1, const float4& x0,
                                          const float4& w0, const float4& w1,
                                          const float4& w2, const float4& w3,
                                          float m) {
    f32x4 o;
    o.x = fmaf(x3.x, w0.x, fmaf(x2.x, w0.y, fmaf(x1.x, w0.z, x0.x * w0.w)));
    o.y = fmaf(x3.y, w1.x, fmaf(x2.y, w1.y, fmaf(x1.y, w1.z, x0.y * w1.w)));
    o.z = fmaf(x3.z, w2.x, fmaf(x2.z, w2.y, fmaf(x1.z, w2.z, x0.z * w2.w)));
    o.w = fmaf(x3.w, w3.x, fmaf(x2.w, w3.y, fmaf(x1.w, w3.z, x0.w * w3.w)));
    o.x *= m; o.y *= m; o.z *= m; o.w *= m;
    return o;
}

__global__ __launch_bounds__(TPB, 4) void budgie_dwconv1d_kernel(
    const float* __restrict__ x,     // [B,S,H]
    const float* __restrict__ w,     // [H,K]
    const float* __restrict__ mask,  // [B,S]
    float* __restrict__ y)           // [B,S,H]
{
    __shared__ float4 ring[4][TILE4];                // 64 KiB -> 2 blocks/CU

    const int t  = threadIdx.x;                      // column h4, 0..511
    const int wv = t >> 6;                           // wave id 0..7
    const int ln = t & 63;                           // lane id
    const int r0 = blockIdx.x * SPANR;               // first row of span

    const float4* x4 = (const float4*)x;
    const float4* w4 = (const float4*)w;
    f32x4* y4 = (f32x4*)y;

    // Per-channel taps (column t loop-invariant).
    const float4 w0 = w4[t * 4 + 0];
    const float4 w1 = w4[t * 4 + 1];
    const float4 w2 = w4[t * 4 + 2];
    const float4 w3 = w4[t * 4 + 3];

    const float4 zero4 = make_float4(0.f, 0.f, 0.f, 0.f);

    // Halo registers: rows r0-1, r0-2, r0-3 (issued BEFORE the DMAs -> older in
    // vmcnt order, so iter 0's counted wait covers them too).
    float4 h1, h2, h3;
    if ((r0 & (S_ - 1)) != 0) {                      // uniform; ==0 iff batch start
        h1 = x4[(long)(r0 - 1) * H4 + t];
        h2 = x4[(long)(r0 - 2) * H4 + t];
        h3 = x4[(long)(r0 - 3) * H4 + t];
    } else {
        h1 = h2 = h3 = zero4;                        // causal zero-pad
    }

    // Prologue: prime ring with tiles 0..2 (fire-and-forget, no wait).
    stage2(x4 + (long)(r0 + 0 * TROWS) * H4, ring[0], wv, ln);
    stage2(x4 + (long)(r0 + 1 * TROWS) * H4, ring[1], wv, ln);
    stage2(x4 + (long)(r0 + 2 * TROWS) * H4, ring[2], wv, ln);

    #pragma unroll
    for (int i = 0; i < NT; ++i) {
        // (1) Keep the read queue at depth 3 tiles: issue tile i+3 NOW.
        if (i + 3 < NT)
            stage2(x4 + (long)(r0 + (i + 3) * TROWS) * H4, ring[(i + 3) & 3],
                   wv, ln);

        // (2) Exact counted wait for tile i (never 0; stores free-run).
        if (i == 0 || i == NT - 1)
            asm volatile("s_waitcnt vmcnt(6)" ::: "memory");
        else if (i == 1 || i == NT - 2)
            asm volatile("s_waitcnt vmcnt(8)" ::: "memory");
        else if (i == 2 || i == NT - 3)
            asm volatile("s_waitcnt vmcnt(10)" ::: "memory");
        else
            asm volatile("s_waitcnt vmcnt(12)" ::: "memory");
        __builtin_amdgcn_sched_barrier(0);
        __builtin_amdgcn_s_barrier();                // all waves' tile-i slices in

        // (3) Compute tile i: 2 rows from LDS + register halo.
        const int R  = r0 + i * TROWS;
        const int Ru = __builtin_amdgcn_readfirstlane(R);   // mask via s_load
        const float4 L0 = ring[i & 3][0 * H4 + t];   // ds_read_b128, conflict-free
        const float4 L1 = ring[i & 3][1 * H4 + t];

        f32x4 o0 = conv_row(h3, h2, h1, L0, w0, w1, w2, w3, mask[Ru + 0]);
        f32x4 o1 = conv_row(h2, h1, L0, L1, w0, w1, w2, w3, mask[Ru + 1]);

        __builtin_nontemporal_store(o0, y4 + (long)(R + 0) * H4 + t);
        __builtin_nontemporal_store(o1, y4 + (long)(R + 1) * H4 + t);

        // (4) Rotate halo for next tile (registers only; LDS back-read illegal).
        h3 = h1; h2 = L0; h1 = L1;

        // (5) All waves done reading ring[i&3] before iter i+1 DMAs into
        //     ring[(i+4)&3] == ring[i&3]. No vmcnt drain here.
        __builtin_amdgcn_s_barrier();
    }
}

extern "C" void kernel_launch(void* const* d_in, const int* in_sizes, int n_in,
                              void* d_out, int out_size, void* d_ws, size_t ws_size,
                              hipStream_t stream) {
    const float* x    = (const float*)d_in[0];   // hidden_states [B,S,H]
    const float* w    = (const float*)d_in[1];   // weight [H,K]
    const float* mask = (const float*)d_in[2];   // attention_mask_2d [B,S]
    float* y = (float*)d_out;

    budgie_dwconv1d_kernel<<<dim3(NBLK), TPB, 0, stream>>>(x, w, mask, y);
}